// Round 4
// baseline (430.437 us; speedup 1.0000x reference)
//
#include <hip/hip_runtime.h>
#include <hip/hip_bf16.h>
#include <cmath>

namespace {
constexpr int Pn = 128;
constexpr int Hn = 512;
constexpr int Ln = 8192;
constexpr int BS = 8;
// ws byte layout:
//   [0, 2048)             Lam fp32: [0,128) L_re | [128,256) L_im | [256,384) A32_re | [384,512) A32_im
//   [2048, 264192)        Bmat bf16 [256][512]  (rows 0..127 re, 128..255 im)
//   [264192, 526336)      Cmat bf16 [512][256]  (+2*C_re | -2*C_im)
//   [526336, 2623488)     End  fp32 [8][256 chunks][2][128]   (local chunk-end states)
//   [2623488, 4720640)    Carry fp32 [8][256 chunks][2][128]  (exclusive carries)
//   [4720640, ...)        Bu fp32 [NB][8192][256]  ([l][p]).  After scan_apply, each
//                         1024B row's first 512B are REUSED in place as 256 bf16 xs.
constexpr size_t OFF_BMAT = 2048;
constexpr size_t OFF_CMAT = 264192;
constexpr size_t OFF_END  = 526336;
constexpr size_t OFF_CAR  = 2623488;
constexpr size_t HEADB    = 4720640;
constexpr size_t SZ_BU = (size_t)256 * Ln * 4;     // 8388608 per batch
}

typedef __attribute__((ext_vector_type(4))) float f32x4;
typedef __attribute__((ext_vector_type(8))) short bf16x8;

static __device__ inline short f2bf(float x) {
  __hip_bfloat16 h = __float2bfloat16(x);
  return *(short*)&h;
}

// ---------------------------------------------------------------- precompute
__global__ void precompute_kernel(const float* __restrict__ Lre,
                                  const float* __restrict__ Lim,
                                  const float* __restrict__ Bin,
                                  const float* __restrict__ Cin,
                                  const float* __restrict__ lstep,
                                  float* __restrict__ Lam,
                                  __hip_bfloat16* __restrict__ Bmat,
                                  __hip_bfloat16* __restrict__ Cmat) {
  int tid = blockIdx.x * blockDim.x + threadIdx.x;
  if (tid < 2 * Pn * Hn) {
    int r = tid >> 9;          // row in [0,256)
    int h = tid & (Hn - 1);
    int p = r & (Pn - 1);
    float st = expf(lstep[p]);
    float lr = Lre[p], li = Lim[p];
    float er = expf(lr * st);
    float cr = er * cosf(li * st);
    float ci = er * sinf(li * st);
    float nr = cr - 1.0f, ni = ci;
    float inv = 1.0f / (lr * lr + li * li);
    float wr = (nr * lr + ni * li) * inv;
    float wi = (ni * lr - nr * li) * inv;
    float btr = Bin[(p * Hn + h) * 2 + 0];
    float bti = Bin[(p * Hn + h) * 2 + 1];
    float val = (r < Pn) ? (wr * btr - wi * bti) : (wr * bti + wi * btr);
    Bmat[tid] = __float2bfloat16(val);
  } else if (tid < 4 * Pn * Hn) {
    int j = tid - 2 * Pn * Hn;
    int h = j >> 8;
    int c = j & 255;
    int p = c & (Pn - 1);
    float v = (c < Pn) ? 2.0f * Cin[(h * Pn + p) * 2 + 0]
                       : -2.0f * Cin[(h * Pn + p) * 2 + 1];
    Cmat[j] = __float2bfloat16(v);
  } else if (tid < 4 * Pn * Hn + 512) {
    int j = tid - 4 * Pn * Hn;
    int p = j & 127;
    int sel = j >> 7;   // 0: L_re  1: L_im  2: A32_re  3: A32_im
    float st = expf(lstep[p]);
    float lr = Lre[p], li = Lim[p];
    float sc = (sel < 2) ? st : 32.0f * st;
    float er = expf(lr * sc);
    Lam[(sel >> 1) * 256 + (sel & 1) * 128 + p] =
        (sel & 1) ? er * sinf(li * sc) : er * cosf(li * sc);
  }
}

// ---------------------------------------------------------------- MFMA GEMM1 (BM=256 full-M, BN=64)
// Bu_t[bz][l][256] = (Bmat[256][512] @ U[(b0+bz)][512][8192])^T
// A-operand loaded DIRECT from global (Bmat L2-hot); only U transpose+cvt goes
// through LDS, double-buffered (prefetch k+1 before compute k), 1 barrier/step.
__global__ __launch_bounds__(256) void gemm1_kernel(
    const __hip_bfloat16* __restrict__ Amat,  // [256][512]
    const float* __restrict__ U,              // [8][512][8192]
    float* __restrict__ Bu,                   // [NB][8192][256]
    int b0) {
  __shared__ __align__(16) short Bs[2][64 * 40];   // 2 x 5 KB (stride 40 shorts)
  const int t = threadIdx.x;
  const int lane = t & 63, w = t >> 6;
  const int n0 = blockIdx.x * 64;
  const int bz = blockIdx.z;
  const float* Ub = U + (size_t)(b0 + bz) * Hn * Ln;
  const short* Ap = (const short*)Amat;
  const int lr = lane & 15, lk = (lane >> 4) * 8;
  const int bn = t & 63, bkg = t >> 6;   // staging: col n, k-octet

  // prologue: stage k-step 0 into buffer 0
  {
    float v[8];
#pragma unroll
    for (int j = 0; j < 8; j++)
      v[j] = Ub[(size_t)(bkg * 8 + j) * Ln + n0 + bn];
    bf16x8 pk;
#pragma unroll
    for (int j = 0; j < 8; j++) pk[j] = f2bf(v[j]);
    *(bf16x8*)&Bs[0][bn * 40 + bkg * 8] = pk;
  }
  __syncthreads();

  f32x4 acc[4][4] = {};
  int cur = 0;
  for (int ks = 0; ks < 16; ks++) {
    const int k0 = ks * 32;
    // 1. issue next k-step's U loads (in flight during MFMA)
    float v[8];
    if (ks < 15) {
#pragma unroll
      for (int j = 0; j < 8; j++)
        v[j] = Ub[(size_t)(k0 + 32 + bkg * 8 + j) * Ln + n0 + bn];
    }
    // 2. compute current step: A direct from global, B from LDS[cur]
    bf16x8 af[4], bfr[4];
#pragma unroll
    for (int mt = 0; mt < 4; mt++)
      af[mt] = *(const bf16x8*)&Ap[(size_t)(64 * w + 16 * mt + lr) * Hn + k0 + lk];
#pragma unroll
    for (int nt = 0; nt < 4; nt++)
      bfr[nt] = *(const bf16x8*)&Bs[cur][(16 * nt + lr) * 40 + lk];
#pragma unroll
    for (int mt = 0; mt < 4; mt++)
#pragma unroll
      for (int nt = 0; nt < 4; nt++)
        acc[mt][nt] = __builtin_amdgcn_mfma_f32_16x16x32_bf16(
            af[mt], bfr[nt], acc[mt][nt], 0, 0, 0);
    // 3. land prefetched loads into LDS[nxt]
    if (ks < 15) {
      bf16x8 pk;
#pragma unroll
      for (int j = 0; j < 8; j++) pk[j] = f2bf(v[j]);
      *(bf16x8*)&Bs[cur ^ 1][bn * 40 + bkg * 8] = pk;
    }
    __syncthreads();
    cur ^= 1;
  }
  // epilogue: lane holds 4 consecutive m (=p) for one n (=l) -> one f32x4 store
  const int row4 = (lane >> 4) * 4, col = lane & 15;
  float* Bub = Bu + (size_t)bz * Ln * 256;
#pragma unroll
  for (int mt = 0; mt < 4; mt++)
#pragma unroll
    for (int nt = 0; nt < 4; nt++) {
      int n = n0 + 16 * nt + col;
      int m = 64 * w + 16 * mt + row4;
      *(f32x4*)&Bub[(size_t)n * 256 + m] = acc[mt][nt];
    }
}

// ---------------------------------------------------------------- scan phase 1: local chunk ends
__global__ __launch_bounds__(256) void scan_ends_kernel(const float* __restrict__ Bu,
                                                        const float* __restrict__ Lam,
                                                        float* __restrict__ End) {
  const int bz = blockIdx.y;
  const int t = threadIdx.x;
  const int c = blockIdx.x * 2 + (t >> 7);
  const int p = t & 127;
  const float Ar = Lam[p], Ai = Lam[128 + p];
  const float* base = Bu + ((size_t)bz * Ln + (size_t)c * 32) * 256;
  float br[32], bi[32];
#pragma unroll
  for (int i = 0; i < 32; i++) br[i] = base[(size_t)i * 256 + p];
#pragma unroll
  for (int i = 0; i < 32; i++) bi[i] = base[(size_t)i * 256 + 128 + p];
  float xr = 0.f, xi = 0.f;
#pragma unroll
  for (int i = 0; i < 32; i++) {
    float nr = fmaf(Ar, xr, fmaf(-Ai, xi, br[i]));
    float ni = fmaf(Ar, xi, fmaf(Ai, xr, bi[i]));
    xr = nr; xi = ni;
  }
  float* E = End + ((size_t)bz * 256 + c) * 256;
  E[p] = xr;
  E[128 + p] = xi;
}

// ---------------------------------------------------------------- scan phase 2: carry propagation
__global__ __launch_bounds__(128) void carry_kernel(const float* __restrict__ End,
                                                    float* __restrict__ Carry,
                                                    const float* __restrict__ Lam) {
  const int bz = blockIdx.x;
  const int p = threadIdx.x;
  const float a32r = Lam[256 + p], a32i = Lam[384 + p];
  const float* E = End + (size_t)bz * 256 * 256;
  float* C = Carry + (size_t)bz * 256 * 256;
  float xr = 0.f, xi = 0.f;
  float er0[4], ei0[4], er1[4], ei1[4];
#pragma unroll
  for (int q = 0; q < 4; q++) {
    er0[q] = E[(size_t)q * 256 + p];
    ei0[q] = E[(size_t)q * 256 + 128 + p];
  }
  for (int c0 = 0; c0 < 256; c0 += 8) {
#pragma unroll
    for (int q = 0; q < 4; q++) {
      er1[q] = E[(size_t)(c0 + 4 + q) * 256 + p];
      ei1[q] = E[(size_t)(c0 + 4 + q) * 256 + 128 + p];
    }
#pragma unroll
    for (int q = 0; q < 4; q++) {
      C[(size_t)(c0 + q) * 256 + p] = xr;
      C[(size_t)(c0 + q) * 256 + 128 + p] = xi;
      float nr = fmaf(a32r, xr, fmaf(-a32i, xi, er0[q]));
      float ni = fmaf(a32r, xi, fmaf(a32i, xr, ei0[q]));
      xr = nr; xi = ni;
    }
#pragma unroll
    for (int q = 0; q < 4; q++) {
      int cn = c0 + 8 + q;
      if (cn < 256) {
        er0[q] = E[(size_t)cn * 256 + p];
        ei0[q] = E[(size_t)cn * 256 + 128 + p];
      }
    }
#pragma unroll
    for (int q = 0; q < 4; q++) {
      C[(size_t)(c0 + 4 + q) * 256 + p] = xr;
      C[(size_t)(c0 + 4 + q) * 256 + 128 + p] = xi;
      float nr = fmaf(a32r, xr, fmaf(-a32i, xi, er1[q]));
      float ni = fmaf(a32r, xi, fmaf(a32i, xr, ei1[q]));
      xr = nr; xi = ni;
    }
  }
}

// ---------------------------------------------------------------- scan phase 3: seeded local scan
// Reads fp32 Bu rows, writes xs as bf16 IN PLACE into the first 512B of each row
// (MFMA-fragment-ready layout for gemm2). Rows are block-exclusive; the barrier
// separates all fp32 loads from the overlapping bf16 stores.
__global__ __launch_bounds__(256) void scan_apply_kernel(float* __restrict__ Bu,
                                                         const float* __restrict__ Lam,
                                                         const float* __restrict__ Carry) {
  const int bz = blockIdx.y;
  const int t = threadIdx.x;
  const int c = blockIdx.x * 2 + (t >> 7);
  const int p = t & 127;
  const float Ar = Lam[p], Ai = Lam[128 + p];
  float* base = Bu + ((size_t)bz * Ln + (size_t)c * 32) * 256;
  short* outb = (short*)base;           // bf16 view, row stride 512 shorts (1024 B)
  const float* Cg = Carry + ((size_t)bz * 256 + c) * 256;
  float br[32], bi[32];
#pragma unroll
  for (int i = 0; i < 32; i++) br[i] = base[(size_t)i * 256 + p];
#pragma unroll
  for (int i = 0; i < 32; i++) bi[i] = base[(size_t)i * 256 + 128 + p];
  float xr = Cg[p], xi = Cg[128 + p];
  __syncthreads();   // all fp32 reads in this block complete before bf16 overwrite
#pragma unroll
  for (int i = 0; i < 32; i++) {
    float nr = fmaf(Ar, xr, fmaf(-Ai, xi, br[i]));
    float ni = fmaf(Ar, xi, fmaf(Ai, xr, bi[i]));
    xr = nr; xi = ni;
    outb[(size_t)i * 512 + p] = f2bf(nr);
    outb[(size_t)i * 512 + 128 + p] = f2bf(ni);
  }
}

// ---------------------------------------------------------------- MFMA GEMM2 — no LDS, no barriers
// Out[b][H][L] = gelu( Cmat[512][256] @ xs^T + D[h]*U[b][h][l] )
// xs is bf16, row-major [l][256] with 1024B row stride — already in MFMA
// fragment layout, so A and B fragments load straight from global (L2/L3-hot).
__global__ __launch_bounds__(256) void gemm2_kernel(
    const __hip_bfloat16* __restrict__ Cmat,  // [512][256]
    const short* __restrict__ Xs,             // [NB][8192] rows of 256 bf16, stride 512 shorts
    const float* __restrict__ U,              // [8][512][8192]
    const float* __restrict__ Dv,             // [512]
    float* __restrict__ Out, int b0) {
  const int t = threadIdx.x;
  const int lane = t & 63, w = t >> 6;
  const int wm = w >> 1, wn = w & 1;
  const int n0 = blockIdx.x * 128;
  const int m0 = blockIdx.y * 128;
  const int bz = blockIdx.z;
  const int b = b0 + bz;
  const int lr = lane & 15, lk = (lane >> 4) * 8;
  const short* Ap = (const short*)Cmat;
  const short* Bp = Xs + (size_t)bz * Ln * 512;

  f32x4 acc[4][4] = {};
#pragma unroll
  for (int ks = 0; ks < 8; ks++) {
    const int k0 = ks * 32;
    bf16x8 af[4], bfr[4];
#pragma unroll
    for (int mt = 0; mt < 4; mt++)
      af[mt] = *(const bf16x8*)&Ap[(size_t)(m0 + 64 * wm + 16 * mt + lr) * 256 + k0 + lk];
#pragma unroll
    for (int nt = 0; nt < 4; nt++)
      bfr[nt] = *(const bf16x8*)&Bp[(size_t)(n0 + 64 * wn + 16 * nt + lr) * 512 + k0 + lk];
#pragma unroll
    for (int mt = 0; mt < 4; mt++)
#pragma unroll
      for (int nt = 0; nt < 4; nt++)
        acc[mt][nt] = __builtin_amdgcn_mfma_f32_16x16x32_bf16(
            af[mt], bfr[nt], acc[mt][nt], 0, 0, 0);
  }
  const int row4 = (lane >> 4) * 4, col = lane & 15;
#pragma unroll
  for (int mt = 0; mt < 4; mt++) {
#pragma unroll
    for (int r = 0; r < 4; r++) {
      int h = m0 + 64 * wm + 16 * mt + row4 + r;
      float dh = Dv[h];
      const float* Urow = U + ((size_t)b * Hn + h) * Ln;
      float* Orow = Out + ((size_t)b * Hn + h) * Ln;
#pragma unroll
      for (int nt = 0; nt < 4; nt++) {
        int n = n0 + 64 * wn + 16 * nt + col;
        float y = acc[mt][nt][r] + dh * Urow[n];
        // tanh-form gelu: y * sigmoid(2*0.7978845608*(y + 0.044715 y^3)), tail-safe
        float u2 = y * (0.7978845608f + 0.0356774081f * y * y);
        Orow[n] = y / (1.0f + __expf(-2.0f * u2));
      }
    }
  }
}

// ---------------------------------------------------------------- launch
extern "C" void kernel_launch(void* const* d_in, const int* in_sizes, int n_in,
                              void* d_out, int out_size, void* d_ws, size_t ws_size,
                              hipStream_t stream) {
  const float* U   = (const float*)d_in[0];
  const float* Lre = (const float*)d_in[1];
  const float* Lim = (const float*)d_in[2];
  const float* Bin = (const float*)d_in[3];
  const float* Cin = (const float*)d_in[4];
  const float* Dv  = (const float*)d_in[5];
  const float* ls  = (const float*)d_in[6];
  float* out = (float*)d_out;

  char* wsb = (char*)d_ws;
  float* Lam = (float*)wsb;
  __hip_bfloat16* Bmat = (__hip_bfloat16*)(wsb + OFF_BMAT);
  __hip_bfloat16* Cmat = (__hip_bfloat16*)(wsb + OFF_CMAT);
  float* End = (float*)(wsb + OFF_END);
  float* Cy  = (float*)(wsb + OFF_CAR);
  float* Bu  = (float*)(wsb + HEADB);

  int NB = 8;
  while (NB > 1 && ws_size < HEADB + (size_t)NB * SZ_BU)
    NB >>= 1;

  precompute_kernel<<<(4 * Pn * Hn + 512 + 255) / 256, 256, 0, stream>>>(
      Lre, Lim, Bin, Cin, ls, Lam, Bmat, Cmat);

  for (int b0 = 0; b0 < BS; b0 += NB) {
    gemm1_kernel<<<dim3(Ln / 64, 1, NB), 256, 0, stream>>>(Bmat, U, Bu, b0);
    scan_ends_kernel<<<dim3(128, NB), 256, 0, stream>>>(Bu, Lam, End);
    carry_kernel<<<dim3(NB), 128, 0, stream>>>(End, Cy, Lam);
    scan_apply_kernel<<<dim3(128, NB), 256, 0, stream>>>(Bu, Lam, Cy);
    gemm2_kernel<<<dim3(Ln / 128, Hn / 128, NB), 256, 0, stream>>>(
        Cmat, (const short*)Bu, U, Dv, out, b0);
  }
}